// Round 13
// baseline (1390.959 us; speedup 1.0000x reference)
//
#include <hip/hip_runtime.h>
#include <hip/hip_fp16.h>
#include <stdint.h>

#define BB 8
#define NN 4096
#define ATTRD 16
#define HD 64
#define STEPS 8
#define NODES (BB*NN)      // 32768
#define ECAP 96            // nnz/row ~ Poisson(41); P(>=96) astronomically small
#define KPAD 196           // xs row stride in floats (784 B, 16B-aligned, non-pow2)

typedef _Float16 half8 __attribute__((ext_vector_type(8)));
typedef float floatx4 __attribute__((ext_vector_type(4)));
typedef unsigned long long ull;

// ---------------- init: h = relu(attr @ Wi^T + bi); fp32 + fp16 mirror + dummy rows ----------
__global__ void init_h_kernel(const float* __restrict__ attr, const float* __restrict__ Wi,
                              const float* __restrict__ bi, float* __restrict__ h,
                              __half* __restrict__ h16a, __half* __restrict__ h16b) {
    int idx = blockIdx.x * blockDim.x + threadIdx.x;   // node*64 + l
    if (idx >= (NODES + 1) * HD) return;
    if (idx >= NODES * HD) {                           // dummy row (index NODES): zeros, both bufs
        h16a[idx] = __float2half(0.f);
        h16b[idx] = __float2half(0.f);
        return;
    }
    int node = idx >> 6, l = idx & 63;
    const float* a = attr + node * ATTRD;
    const float* w = Wi + l * ATTRD;
    float acc = bi[l];
#pragma unroll
    for (int k = 0; k < ATTRD; k++) acc += a[k] * w[k];
    float r = acc > 0.f ? acc : 0.f;
    h[idx] = r;
    h16a[idx] = __float2half(r);
}

// ---------------- weight prep: split-fp16 MFMA B-fragments (r8-proven) ----------------
__global__ void wprep_kernel(const float* __restrict__ Wz, const float* __restrict__ Wr,
                             const float* __restrict__ Wh,
                             _Float16* __restrict__ wf_hi, _Float16* __restrict__ wf_lo) {
    int t = blockIdx.x * blockDim.x + threadIdx.x;
    if (t >= 3 * 4 * 6 * 64 * 8) return;
    int mat = t / 12288, rem = t % 12288;
    int tile = rem / 3072, rem2 = rem % 3072;
    int kc = rem2 / 512, rem3 = rem2 % 512;
    int lane = rem3 / 8, j = rem3 % 8;
    int k = kc * 32 + (lane >> 4) * 8 + j;
    int och = tile * 16 + (lane & 15);
    const float* W = (mat == 0) ? Wz : (mat == 1) ? Wr : Wh;
    float v = W[och * 192 + k];
    _Float16 hi = (_Float16)v;
    wf_hi[t] = hi;
    wf_lo[t] = (_Float16)(v - (float)hi);
}

// ---------------- ELL build: one wave per row; in-edges atomic-free, out-edges folded (r11) ----
__global__ __launch_bounds__(256) void count_rows_kernel(const float4* __restrict__ A4,
                                                         int* __restrict__ cnt_in,
                                                         int* __restrict__ edge_in,
                                                         int* __restrict__ cnt_out,
                                                         int* __restrict__ edge_out) {
    int wave = threadIdx.x >> 6, l = threadIdx.x & 63;
    int row = blockIdx.x * 4 + wave;                   // 0..32767
    const float4* rp = A4 + (size_t)row * 1024;
    ull mask_lt = (l == 63) ? ~0ull >> 1 : ((1ull << (l + 1)) - 1) >> 1; // bits < l
    float4 v[16];
#pragma unroll
    for (int t = 0; t < 16; t++) v[t] = rp[t * 64 + l];   // 16 coalesced 1KB loads in flight
    int colbase = (row >> 12) << 12;                      // batch * 4096
    int run = 0;
    int* erow = edge_in + row * ECAP;
#pragma unroll
    for (int t = 0; t < 16; t++) {
        ull b0 = __ballot(v[t].x != 0.f);
        ull b1 = __ballot(v[t].y != 0.f);
        ull b2 = __ballot(v[t].z != 0.f);
        ull b3 = __ballot(v[t].w != 0.f);
        int pre = __popcll(b0 & mask_lt) + __popcll(b1 & mask_lt) +
                  __popcll(b2 & mask_lt) + __popcll(b3 & mask_lt);
        float vv[4] = {v[t].x, v[t].y, v[t].z, v[t].w};
        int jbase = (t * 64 + l) * 4;
        int inner = 0;
#pragma unroll
        for (int q = 0; q < 4; q++) {
            if (vv[q] != 0.f) {
                int col = colbase | (jbase + q);
                int slot = run + pre + inner;
                if (slot < ECAP) erow[slot] = col;
                inner++;
                int s2 = atomicAdd(&cnt_out[col], 1);      // distinct cols per lane
                if (s2 < ECAP) edge_out[col * ECAP + s2] = row;
            }
        }
        run += __popcll(b0) + __popcll(b1) + __popcll(b2) + __popcll(b3);
    }
    if (l == 0) cnt_in[row] = run;
}

// ---------------- fused step: r12 gather (4 dual-dir waves) + M=4 MFMA gate epilogue ----------
// 8192 blocks x 256 thr; wave w gathers node node_base+w (both dirs, r12 fp16-tree volleys)
// into LDS xs rows; then the r8 split-fp16 gate runs with A rows = 4 nodes (m&3 duplication,
// dup D-rows discarded). Double-buffered h: reads h/h16 cur, writes nxt. xs never hits global.
__global__ __launch_bounds__(256) void step_kernel(
        const uint4* __restrict__ h4, const float* __restrict__ hg,
        const int* __restrict__ cnt_in, const int* __restrict__ edge_in,
        const int* __restrict__ cnt_out, const int* __restrict__ edge_out,
        const _Float16* __restrict__ wf_hi, const _Float16* __restrict__ wf_lo,
        const float* __restrict__ bz, const float* __restrict__ br,
        const float* __restrict__ bh,
        float* __restrict__ h_out, __half* __restrict__ h16_out) {
    __shared__ float xs_t[4][KPAD];            // 3.1 KB: [a_in | a_out | h] per node
    __shared__ float h32s[4][64];              // 1 KB fp32 h for epilogue

    int bid = blockIdx.x;                      // 8192
    int batch = bid & 7;                       // XCD swizzle
    int group = bid >> 3;                      // 0..1023
    int node_base = (batch << 12) + group * 4;
    int tid = threadIdx.x;
    int wave = tid >> 6, l = tid & 63;

    // ---- stage fp32 h (1 KB coalesced load; latency hidden under gathers) ----
    {
        int nl = tid >> 6, c = tid & 63;
        float v = hg[((node_base + nl) << 6) | c];
        h32s[nl][c] = v;
        xs_t[nl][128 + c] = v;
    }

    // ---- gather phase (r12-proven): node = node_base + wave, dual-dir ----
    int node = node_base + wave;
    int sub = l >> 3;                          // edge sub-slot (0..7)
    int part = l & 7;                          // 16B chunk within 128B row
    int ni = cnt_in[node];  if (ni > ECAP) ni = ECAP;
    int no = cnt_out[node]; if (no > ECAP) no = ECAP;
    const int* ei = edge_in + node * ECAP;
    const int* eo = edge_out + node * ECAP;
    int ei0 = ei[l], ei1 = ei[64 + (l & 31)];
    int eo0 = eo[l], eo1 = eo[64 + (l & 31)];
    float ai[8] = {0.f, 0.f, 0.f, 0.f, 0.f, 0.f, 0.f, 0.f};
    float ao[8] = {0.f, 0.f, 0.f, 0.f, 0.f, 0.f, 0.f, 0.f};
    int nmax = ni > no ? ni : no;
    for (int s = 0; s < nmax; s += 32) {
        uint4 gA[4], gB[4];
#pragma unroll
        for (int k = 0; k < 4; k++) {
            int il = s + k * 8 + sub;
            int gi = (il < 64) ? __shfl(ei0, il) : __shfl(ei1, il - 64);
            int go = (il < 64) ? __shfl(eo0, il) : __shfl(eo1, il - 64);
            gi = (il < ni) ? gi : NODES;       // dummy zero row
            go = (il < no) ? go : NODES;
            gA[k] = h4[(gi << 3) | part];      // 8 independent gathers in flight
            gB[k] = h4[(go << 3) | part];
        }
        const __half2* hA0 = (const __half2*)&gA[0];
        const __half2* hA1 = (const __half2*)&gA[1];
        const __half2* hA2 = (const __half2*)&gA[2];
        const __half2* hA3 = (const __half2*)&gA[3];
        const __half2* hB0 = (const __half2*)&gB[0];
        const __half2* hB1 = (const __half2*)&gB[1];
        const __half2* hB2 = (const __half2*)&gB[2];
        const __half2* hB3 = (const __half2*)&gB[3];
#pragma unroll
        for (int k = 0; k < 4; k++) {          // 2-level v_pk_add_f16 tree (r12)
            __half2 sA = __hadd2(__hadd2(hA0[k], hA1[k]), __hadd2(hA2[k], hA3[k]));
            __half2 sB = __hadd2(__hadd2(hB0[k], hB1[k]), __hadd2(hB2[k], hB3[k]));
            float2 fA = __half22float2(sA);
            float2 fB = __half22float2(sB);
            ai[2 * k] += fA.x; ai[2 * k + 1] += fA.y;
            ao[2 * k] += fB.x; ao[2 * k + 1] += fB.y;
        }
    }
#pragma unroll
    for (int off = 8; off < 64; off <<= 1) {
#pragma unroll
        for (int k = 0; k < 8; k++) {
            ai[k] += __shfl_xor(ai[k], off);
            ao[k] += __shfl_xor(ao[k], off);
        }
    }
    if (l < 8) {                               // lane l holds channels l*8..l*8+7
        float* dst = &xs_t[wave][0];
        float4 si0 = {ai[0], ai[1], ai[2], ai[3]};
        float4 si1 = {ai[4], ai[5], ai[6], ai[7]};
        float4 so0 = {ao[0], ao[1], ao[2], ao[3]};
        float4 so1 = {ao[4], ao[5], ao[6], ao[7]};
        *(float4*)(dst + l * 8)          = si0;
        *(float4*)(dst + l * 8 + 4)      = si1;
        *(float4*)(dst + 64 + l * 8)     = so0;
        *(float4*)(dst + 64 + l * 8 + 4) = so1;
    }
    __syncthreads();

    // ---- gate phase (r8 split-fp16 MFMA, M=4): A row m -> xs_t[m&3], dup rows discarded ----
    int m = l & 15, q = l >> 4;
    int mm = m & 3;                            // node row (rows 4-15 duplicate 0-3)
    int ch = wave * 16 + m;                    // output channel (C/D col=lane&15)
    const half8* WH = (const half8*)wf_hi;
    const half8* WL = (const half8*)wf_lo;

    floatx4 accz = {0.f, 0.f, 0.f, 0.f};
    floatx4 accr = {0.f, 0.f, 0.f, 0.f};
#pragma unroll
    for (int kc = 0; kc < 6; kc++) {
        const float* xr = &xs_t[mm][kc * 32 + q * 8];
        float4 xa = *(const float4*)xr;
        float4 xb = *(const float4*)(xr + 4);
        float xv[8] = {xa.x, xa.y, xa.z, xa.w, xb.x, xb.y, xb.z, xb.w};
        half8 ahi, alo;
#pragma unroll
        for (int j = 0; j < 8; j++) {
            _Float16 hj = (_Float16)xv[j];
            ahi[j] = hj;
            alo[j] = (_Float16)(xv[j] - (float)hj);
        }
        half8 bzh = WH[((0 * 4 + wave) * 6 + kc) * 64 + l];
        half8 bzl = WL[((0 * 4 + wave) * 6 + kc) * 64 + l];
        half8 brh = WH[((1 * 4 + wave) * 6 + kc) * 64 + l];
        half8 brl = WL[((1 * 4 + wave) * 6 + kc) * 64 + l];
        accz = __builtin_amdgcn_mfma_f32_16x16x32_f16(ahi, bzh, accz, 0, 0, 0);
        accz = __builtin_amdgcn_mfma_f32_16x16x32_f16(alo, bzh, accz, 0, 0, 0);
        accz = __builtin_amdgcn_mfma_f32_16x16x32_f16(ahi, bzl, accz, 0, 0, 0);
        accr = __builtin_amdgcn_mfma_f32_16x16x32_f16(ahi, brh, accr, 0, 0, 0);
        accr = __builtin_amdgcn_mfma_f32_16x16x32_f16(alo, brh, accr, 0, 0, 0);
        accr = __builtin_amdgcn_mfma_f32_16x16x32_f16(ahi, brl, accr, 0, 0, 0);
    }
    float bzv = bz[ch], brv = br[ch], bhv = bh[ch];
    float zreg[4], hvreg[4], rh[4];
#pragma unroll
    for (int rg = 0; rg < 4; rg++) {           // C/D row = q*4+rg; real rows only for q==0
        float z = 1.f / (1.f + __expf(-(accz[rg] + bzv)));
        float r = 1.f / (1.f + __expf(-(accr[rg] + brv)));
        float hv = h32s[rg & 3][ch];
        zreg[rg] = z; hvreg[rg] = hv; rh[rg] = r * hv;
    }
    __syncthreads();                           // all zr A-frag reads of slots 128+ done
    if (q == 0) {
#pragma unroll
        for (int rg = 0; rg < 4; rg++) xs_t[rg][128 + ch] = rh[rg];
    }
    __syncthreads();

    floatx4 acch = {0.f, 0.f, 0.f, 0.f};
#pragma unroll
    for (int kc = 0; kc < 6; kc++) {
        const float* xr = &xs_t[mm][kc * 32 + q * 8];
        float4 xa = *(const float4*)xr;
        float4 xb = *(const float4*)(xr + 4);
        float xv[8] = {xa.x, xa.y, xa.z, xa.w, xb.x, xb.y, xb.z, xb.w};
        half8 ahi, alo;
#pragma unroll
        for (int j = 0; j < 8; j++) {
            _Float16 hj = (_Float16)xv[j];
            ahi[j] = hj;
            alo[j] = (_Float16)(xv[j] - (float)hj);
        }
        half8 bhh = WH[((2 * 4 + wave) * 6 + kc) * 64 + l];
        half8 bhl = WL[((2 * 4 + wave) * 6 + kc) * 64 + l];
        acch = __builtin_amdgcn_mfma_f32_16x16x32_f16(ahi, bhh, acch, 0, 0, 0);
        acch = __builtin_amdgcn_mfma_f32_16x16x32_f16(alo, bhh, acch, 0, 0, 0);
        acch = __builtin_amdgcn_mfma_f32_16x16x32_f16(ahi, bhl, acch, 0, 0, 0);
    }
    __syncthreads();                           // all hn A-frag reads done before staging overwrite
    if (q == 0) {
#pragma unroll
        for (int rg = 0; rg < 4; rg++) {
            float pre = acch[rg] + bhv;
            float th = 2.f / (1.f + __expf(-2.f * pre)) - 1.f;
            float hv = hvreg[rg];
            xs_t[rg][ch] = hv + zreg[rg] * (th - hv);   // stage h' rows 0-3, cols 0-63
        }
    }
    __syncthreads();
    {
        int nl = tid >> 6, c = tid & 63;       // coalesced 1 KB write per buffer
        float v = xs_t[nl][c];
        int gi = ((node_base + nl) << 6) | c;
        h_out[gi] = v;
        h16_out[gi] = __float2half(v);
    }
}

// ---------------- output: out = h @ Wo^T + bo ----------------
__global__ void out_kernel(const float* __restrict__ h, const float* __restrict__ Wo,
                           const float* __restrict__ bo, float* __restrict__ out) {
    int wid = (blockIdx.x * blockDim.x + threadIdx.x) >> 6;
    int l = threadIdx.x & 63;
    if (wid >= NODES) return;
    float p = h[(wid << 6) | l] * Wo[l];
#pragma unroll
    for (int off = 32; off > 0; off >>= 1) p += __shfl_down(p, off);
    if (l == 0) out[wid] = p + bo[0];
}

extern "C" void kernel_launch(void* const* d_in, const int* in_sizes, int n_in,
                              void* d_out, int out_size, void* d_ws, size_t ws_size,
                              hipStream_t stream) {
    const float* attr = (const float*)d_in[0];
    const float* adj  = (const float*)d_in[1];
    const float* Wi   = (const float*)d_in[2];
    const float* bi   = (const float*)d_in[3];
    const float* Wz   = (const float*)d_in[4];
    const float* bz   = (const float*)d_in[5];
    const float* Wr   = (const float*)d_in[6];
    const float* br   = (const float*)d_in[7];
    const float* Wh   = (const float*)d_in[8];
    const float* bh   = (const float*)d_in[9];
    const float* Wo   = (const float*)d_in[10];
    const float* bo   = (const float*)d_in[11];
    float* out = (float*)d_out;

    char* ws = (char*)d_ws;
    size_t off = 0;
    auto carve = [&](size_t bytes) { void* p = ws + off; off = (off + bytes + 255) & ~(size_t)255; return p; };
    float*  hA    = (float*)carve((size_t)NODES * HD * 4);            // 8.4 MB
    float*  hB    = (float*)carve((size_t)NODES * HD * 4);            // 8.4 MB
    __half* hA16  = (__half*)carve((size_t)(NODES + 1) * HD * 2);     // 4.2 MB (+dummy row)
    __half* hB16  = (__half*)carve((size_t)(NODES + 1) * HD * 2);     // 4.2 MB (+dummy row)
    _Float16* wf_hi = (_Float16*)carve(3 * 4 * 6 * 64 * 8 * 2);       // 73.7 KB
    _Float16* wf_lo = (_Float16*)carve(3 * 4 * 6 * 64 * 8 * 2);       // 73.7 KB
    int* cnt_in   = (int*)carve((size_t)NODES * 4);
    int* cnt_out  = (int*)carve((size_t)NODES * 4);
    int* edge_in  = (int*)carve((size_t)NODES * ECAP * 4);            // 12.6 MB
    int* edge_out = (int*)carve((size_t)NODES * ECAP * 4);            // 12.6 MB

    hipMemsetAsync(cnt_out, 0, (size_t)NODES * 4, stream);            // cnt_in needs no memset

    init_h_kernel<<<((NODES + 1) * HD + 255) / 256, 256, 0, stream>>>(attr, Wi, bi, hA, hA16, hB16);
    wprep_kernel<<<(3 * 4 * 6 * 64 * 8 + 255) / 256, 256, 0, stream>>>(Wz, Wr, Wh, wf_hi, wf_lo);
    count_rows_kernel<<<NODES / 4, 256, 0, stream>>>((const float4*)adj, cnt_in, edge_in,
                                                     cnt_out, edge_out);

    const float* hc = hA; const __half* hc16 = hA16;
    float* hx = hB; __half* hx16 = hB16;
    for (int step = 0; step < STEPS; ++step) {
        step_kernel<<<NODES / 4, 256, 0, stream>>>(
            (const uint4*)hc16, hc, cnt_in, edge_in, cnt_out, edge_out,
            wf_hi, wf_lo, bz, br, bh, hx, hx16);
        const float* tf = hc; hc = hx; hx = (float*)tf;
        const __half* th = hc16; hc16 = hx16; hx16 = (__half*)th;
    }
    out_kernel<<<NODES * HD / 256, 256, 0, stream>>>(hc, Wo, bo, out);
}

// Round 14
// 1176.489 us; speedup vs baseline: 1.1823x; 1.1823x over previous
//
#include <hip/hip_runtime.h>
#include <hip/hip_fp16.h>
#include <stdint.h>

#define BB 8
#define NN 4096
#define ATTRD 16
#define HD 64
#define STEPS 8
#define NODES (BB*NN)      // 32768
#define ECAP 96            // nnz/row ~ Poisson(41); P(>=96) astronomically small
#define KPAD 196           // xs_t row stride in floats

typedef _Float16 half8 __attribute__((ext_vector_type(8)));
typedef float floatx4 __attribute__((ext_vector_type(4)));
typedef unsigned long long ull;

// ---------------- init: h = relu(attr @ Wi^T + bi); fp32 master + fp16 mirror + zero pad row ----
__global__ void init_h_kernel(const float* __restrict__ attr, const float* __restrict__ Wi,
                              const float* __restrict__ bi, float* __restrict__ h,
                              __half* __restrict__ h16) {
    int idx = blockIdx.x * blockDim.x + threadIdx.x;   // node*64 + l
    if (idx >= (NODES + 1) * HD) return;
    if (idx >= NODES * HD) {                           // dummy row (index NODES): zeros
        h16[idx] = __float2half(0.f);
        return;
    }
    int node = idx >> 6, l = idx & 63;
    const float* a = attr + node * ATTRD;
    const float* w = Wi + l * ATTRD;
    float acc = bi[l];
#pragma unroll
    for (int k = 0; k < ATTRD; k++) acc += a[k] * w[k];
    float r = acc > 0.f ? acc : 0.f;
    h[idx] = r;
    h16[idx] = __float2half(r);
}

// ---------------- weight prep: split-fp16 MFMA B-fragments (r8-proven) ----------------
__global__ void wprep_kernel(const float* __restrict__ Wz, const float* __restrict__ Wr,
                             const float* __restrict__ Wh,
                             _Float16* __restrict__ wf_hi, _Float16* __restrict__ wf_lo) {
    int t = blockIdx.x * blockDim.x + threadIdx.x;
    if (t >= 3 * 4 * 6 * 64 * 8) return;
    int mat = t / 12288, rem = t % 12288;
    int tile = rem / 3072, rem2 = rem % 3072;
    int kc = rem2 / 512, rem3 = rem2 % 512;
    int lane = rem3 / 8, j = rem3 % 8;
    int k = kc * 32 + (lane >> 4) * 8 + j;
    int och = tile * 16 + (lane & 15);
    const float* W = (mat == 0) ? Wz : (mat == 1) ? Wr : Wh;
    float v = W[och * 192 + k];
    _Float16 hi = (_Float16)v;
    wf_hi[t] = hi;
    wf_lo[t] = (_Float16)(v - (float)hi);
}

// ---------------- ELL build: one wave per row; in-edges atomic-free, out-edges folded (r11) ----
__global__ __launch_bounds__(256) void count_rows_kernel(const float4* __restrict__ A4,
                                                         int* __restrict__ cnt_in,
                                                         int* __restrict__ edge_in,
                                                         int* __restrict__ cnt_out,
                                                         int* __restrict__ edge_out) {
    int wave = threadIdx.x >> 6, l = threadIdx.x & 63;
    int row = blockIdx.x * 4 + wave;                   // 0..32767
    const float4* rp = A4 + (size_t)row * 1024;
    ull mask_lt = (l == 63) ? ~0ull >> 1 : ((1ull << (l + 1)) - 1) >> 1; // bits < l
    float4 v[16];
#pragma unroll
    for (int t = 0; t < 16; t++) v[t] = rp[t * 64 + l];   // 16 coalesced 1KB loads in flight
    int colbase = (row >> 12) << 12;                      // batch * 4096
    int run = 0;
    int* erow = edge_in + row * ECAP;
#pragma unroll
    for (int t = 0; t < 16; t++) {
        ull b0 = __ballot(v[t].x != 0.f);
        ull b1 = __ballot(v[t].y != 0.f);
        ull b2 = __ballot(v[t].z != 0.f);
        ull b3 = __ballot(v[t].w != 0.f);
        int pre = __popcll(b0 & mask_lt) + __popcll(b1 & mask_lt) +
                  __popcll(b2 & mask_lt) + __popcll(b3 & mask_lt);
        float vv[4] = {v[t].x, v[t].y, v[t].z, v[t].w};
        int jbase = (t * 64 + l) * 4;
        int inner = 0;
#pragma unroll
        for (int q = 0; q < 4; q++) {
            if (vv[q] != 0.f) {
                int col = colbase | (jbase + q);
                int slot = run + pre + inner;
                if (slot < ECAP) erow[slot] = col;
                inner++;
                int s2 = atomicAdd(&cnt_out[col], 1);      // distinct cols per lane
                if (s2 < ECAP) edge_out[col * ECAP + s2] = row;
            }
        }
        run += __popcll(b0) + __popcll(b1) + __popcll(b2) + __popcll(b3);
    }
    if (l == 0) cnt_in[row] = run;
}

// ---------------- aggregation: xs = [A@h | A^T@h | h] — dual-dir waves, wide gathers (r11) ----
__global__ __launch_bounds__(256) void aggregate_kernel(
        const uint4* __restrict__ h4, const float* __restrict__ h,
        const int* __restrict__ cnt_in, const int* __restrict__ edge_in,
        const int* __restrict__ cnt_out, const int* __restrict__ edge_out,
        float* __restrict__ xs) {
    int bid = blockIdx.x;                      // 8192 blocks
    int batch = bid & 7;                       // XCD swizzle
    int group = bid >> 3;                      // 0..1023
    int wave = threadIdx.x >> 6;
    int node = (batch << 12) + group * 4 + wave;
    int l = threadIdx.x & 63;
    int sub = l >> 3;                          // edge slot within volley of 8
    int part = l & 7;                          // 16B chunk within 128B row
    int ni = cnt_in[node];  if (ni > ECAP) ni = ECAP;
    int no = cnt_out[node]; if (no > ECAP) no = ECAP;
    const int* ei = edge_in + node * ECAP;
    const int* eo = edge_out + node * ECAP;
    // whole edge lists -> registers (4 wave-wide loads, in flight together)
    int ei0 = ei[l], ei1 = ei[64 + (l & 31)];
    int eo0 = eo[l], eo1 = eo[64 + (l & 31)];
    float ai0 = 0.f, ai1 = 0.f, ai2 = 0.f, ai3 = 0.f, ai4 = 0.f, ai5 = 0.f, ai6 = 0.f, ai7 = 0.f;
    float ao0 = 0.f, ao1 = 0.f, ao2 = 0.f, ao3 = 0.f, ao4 = 0.f, ao5 = 0.f, ao6 = 0.f, ao7 = 0.f;
    int nmax = ni > no ? ni : no;
    for (int s = 0; s < nmax; s += 8) {
        int il = s + sub;
        int gi = (il < 64) ? __shfl(ei0, il) : __shfl(ei1, il - 64);
        int go = (il < 64) ? __shfl(eo0, il) : __shfl(eo1, il - 64);
        gi = (il < ni) ? gi : NODES;           // dummy zero row
        go = (il < no) ? go : NODES;
        uint4 gA = h4[(gi << 3) | part];       // two independent gathers in flight
        uint4 gB = h4[(go << 3) | part];
        float2 pA0 = __half22float2(*(__half2*)&gA.x);
        float2 pA1 = __half22float2(*(__half2*)&gA.y);
        float2 pA2 = __half22float2(*(__half2*)&gA.z);
        float2 pA3 = __half22float2(*(__half2*)&gA.w);
        ai0 += pA0.x; ai1 += pA0.y; ai2 += pA1.x; ai3 += pA1.y;
        ai4 += pA2.x; ai5 += pA2.y; ai6 += pA3.x; ai7 += pA3.y;
        float2 pB0 = __half22float2(*(__half2*)&gB.x);
        float2 pB1 = __half22float2(*(__half2*)&gB.y);
        float2 pB2 = __half22float2(*(__half2*)&gB.z);
        float2 pB3 = __half22float2(*(__half2*)&gB.w);
        ao0 += pB0.x; ao1 += pB0.y; ao2 += pB1.x; ao3 += pB1.y;
        ao4 += pB2.x; ao5 += pB2.y; ao6 += pB3.x; ao7 += pB3.y;
    }
    // reduce over the 8 sub-groups (partners share `part`)
#pragma unroll
    for (int off = 8; off < 64; off <<= 1) {
        ai0 += __shfl_xor(ai0, off); ai1 += __shfl_xor(ai1, off);
        ai2 += __shfl_xor(ai2, off); ai3 += __shfl_xor(ai3, off);
        ai4 += __shfl_xor(ai4, off); ai5 += __shfl_xor(ai5, off);
        ai6 += __shfl_xor(ai6, off); ai7 += __shfl_xor(ai7, off);
        ao0 += __shfl_xor(ao0, off); ao1 += __shfl_xor(ao1, off);
        ao2 += __shfl_xor(ao2, off); ao3 += __shfl_xor(ao3, off);
        ao4 += __shfl_xor(ao4, off); ao5 += __shfl_xor(ao5, off);
        ao6 += __shfl_xor(ao6, off); ao7 += __shfl_xor(ao7, off);
    }
    if (l < 8) {                               // lane l holds channels l*8..l*8+7
        float* dst = xs + node * 192;
        float4 si0 = {ai0, ai1, ai2, ai3};
        float4 si1 = {ai4, ai5, ai6, ai7};
        float4 so0 = {ao0, ao1, ao2, ao3};
        float4 so1 = {ao4, ao5, ao6, ao7};
        *(float4*)(dst + l * 8)          = si0;
        *(float4*)(dst + l * 8 + 4)      = si1;
        *(float4*)(dst + 64 + l * 8)     = so0;
        *(float4*)(dst + 64 + l * 8 + 4) = so1;
    }
    xs[node * 192 + 128 + l] = h[(node << 6) | l];   // fp32 master h slot
}

// ---------------- gates via split-fp16 MFMA (r8-proven, fp32-accurate) ----------------
__global__ __launch_bounds__(256) void gate_kernel(
        const float* __restrict__ xs_g,
        const _Float16* __restrict__ wf_hi, const _Float16* __restrict__ wf_lo,
        const float* __restrict__ bz, const float* __restrict__ br,
        const float* __restrict__ bh,
        float* __restrict__ h, __half* __restrict__ h16) {
    __shared__ float xs_t[16][KPAD];     // 12.5 KB
    int bid = blockIdx.x;
    int base = ((bid & 7) << 12) | ((bid >> 3) << 4);   // XCD-swizzled node base
    int tid = threadIdx.x;
    {
        const float4* src = (const float4*)(xs_g + base * 192);
#pragma unroll
        for (int i = 0; i < 3; i++) {
            int idx = tid + i * 256;          // 768 float4s = 16 nodes x 48
            float4 v = src[idx];
            int nl = idx / 48, kb = (idx % 48) * 4;
            *(float4*)&xs_t[nl][kb] = v;
        }
    }
    __syncthreads();
    int wave = tid >> 6, lane = tid & 63;
    int m = lane & 15, q = lane >> 4;
    int ch = wave * 16 + m;                   // global output channel (C/D col=lane&15)
    const half8* WH = (const half8*)wf_hi;
    const half8* WL = (const half8*)wf_lo;

    floatx4 accz = {0.f, 0.f, 0.f, 0.f};
    floatx4 accr = {0.f, 0.f, 0.f, 0.f};
#pragma unroll
    for (int kc = 0; kc < 6; kc++) {
        const float* xr = &xs_t[m][kc * 32 + q * 8];
        float4 xa = *(const float4*)xr;
        float4 xb = *(const float4*)(xr + 4);
        float xv[8] = {xa.x, xa.y, xa.z, xa.w, xb.x, xb.y, xb.z, xb.w};
        half8 ahi, alo;
#pragma unroll
        for (int j = 0; j < 8; j++) {
            _Float16 hj = (_Float16)xv[j];
            ahi[j] = hj;
            alo[j] = (_Float16)(xv[j] - (float)hj);
        }
        half8 bzh = WH[((0 * 4 + wave) * 6 + kc) * 64 + lane];
        half8 bzl = WL[((0 * 4 + wave) * 6 + kc) * 64 + lane];
        half8 brh = WH[((1 * 4 + wave) * 6 + kc) * 64 + lane];
        half8 brl = WL[((1 * 4 + wave) * 6 + kc) * 64 + lane];
        accz = __builtin_amdgcn_mfma_f32_16x16x32_f16(ahi, bzh, accz, 0, 0, 0);
        accz = __builtin_amdgcn_mfma_f32_16x16x32_f16(alo, bzh, accz, 0, 0, 0);
        accz = __builtin_amdgcn_mfma_f32_16x16x32_f16(ahi, bzl, accz, 0, 0, 0);
        accr = __builtin_amdgcn_mfma_f32_16x16x32_f16(ahi, brh, accr, 0, 0, 0);
        accr = __builtin_amdgcn_mfma_f32_16x16x32_f16(alo, brh, accr, 0, 0, 0);
        accr = __builtin_amdgcn_mfma_f32_16x16x32_f16(ahi, brl, accr, 0, 0, 0);
    }
    float bzv = bz[ch], brv = br[ch], bhv = bh[ch];
    float zreg[4], hvreg[4], rh[4];
#pragma unroll
    for (int rg = 0; rg < 4; rg++) {
        int nl = q * 4 + rg;                  // C/D row=(lane>>4)*4+reg -> node
        float z = 1.f / (1.f + __expf(-(accz[rg] + bzv)));
        float r = 1.f / (1.f + __expf(-(accr[rg] + brv)));
        float hv = xs_t[nl][128 + ch];
        zreg[rg] = z; hvreg[rg] = hv; rh[rg] = r * hv;
    }
    __syncthreads();                          // all zr A-frag reads of slots 128+ done
#pragma unroll
    for (int rg = 0; rg < 4; rg++) xs_t[q * 4 + rg][128 + ch] = rh[rg];
    __syncthreads();

    floatx4 acch = {0.f, 0.f, 0.f, 0.f};
#pragma unroll
    for (int kc = 0; kc < 6; kc++) {
        const float* xr = &xs_t[m][kc * 32 + q * 8];
        float4 xa = *(const float4*)xr;
        float4 xb = *(const float4*)(xr + 4);
        float xv[8] = {xa.x, xa.y, xa.z, xa.w, xb.x, xb.y, xb.z, xb.w};
        half8 ahi, alo;
#pragma unroll
        for (int j = 0; j < 8; j++) {
            _Float16 hj = (_Float16)xv[j];
            ahi[j] = hj;
            alo[j] = (_Float16)(xv[j] - (float)hj);
        }
        half8 bhh = WH[((2 * 4 + wave) * 6 + kc) * 64 + lane];
        half8 bhl = WL[((2 * 4 + wave) * 6 + kc) * 64 + lane];
        acch = __builtin_amdgcn_mfma_f32_16x16x32_f16(ahi, bhh, acch, 0, 0, 0);
        acch = __builtin_amdgcn_mfma_f32_16x16x32_f16(alo, bhh, acch, 0, 0, 0);
        acch = __builtin_amdgcn_mfma_f32_16x16x32_f16(ahi, bhl, acch, 0, 0, 0);
    }
    __syncthreads();                          // all hn A-frag reads done before overwrite
#pragma unroll
    for (int rg = 0; rg < 4; rg++) {
        int nl = q * 4 + rg;
        float pre = acch[rg] + bhv;
        float th = 2.f / (1.f + __expf(-2.f * pre)) - 1.f;
        float hv = hvreg[rg];
        xs_t[nl][ch] = hv + zreg[rg] * (th - hv);   // stage h' for coalesced write
    }
    __syncthreads();
    {
        int f = tid * 4;                      // 1024 floats = 16 nodes x 64
        int nl = f >> 6, c = f & 63;
        float4 v = *(const float4*)&xs_t[nl][c];
        int gi = ((base + nl) << 6) | c;
        *(float4*)&h[gi] = v;
        __half2 p0 = {__float2half(v.x), __float2half(v.y)};
        __half2 p1 = {__float2half(v.z), __float2half(v.w)};
        *(__half2*)&h16[gi] = p0;
        *(__half2*)&h16[gi + 2] = p1;
    }
}

// ---------------- output: out = h @ Wo^T + bo ----------------
__global__ void out_kernel(const float* __restrict__ h, const float* __restrict__ Wo,
                           const float* __restrict__ bo, float* __restrict__ out) {
    int wid = (blockIdx.x * blockDim.x + threadIdx.x) >> 6;
    int l = threadIdx.x & 63;
    if (wid >= NODES) return;
    float p = h[(wid << 6) | l] * Wo[l];
#pragma unroll
    for (int off = 32; off > 0; off >>= 1) p += __shfl_down(p, off);
    if (l == 0) out[wid] = p + bo[0];
}

extern "C" void kernel_launch(void* const* d_in, const int* in_sizes, int n_in,
                              void* d_out, int out_size, void* d_ws, size_t ws_size,
                              hipStream_t stream) {
    const float* attr = (const float*)d_in[0];
    const float* adj  = (const float*)d_in[1];
    const float* Wi   = (const float*)d_in[2];
    const float* bi   = (const float*)d_in[3];
    const float* Wz   = (const float*)d_in[4];
    const float* bz   = (const float*)d_in[5];
    const float* Wr   = (const float*)d_in[6];
    const float* br   = (const float*)d_in[7];
    const float* Wh   = (const float*)d_in[8];
    const float* bh   = (const float*)d_in[9];
    const float* Wo   = (const float*)d_in[10];
    const float* bo   = (const float*)d_in[11];
    float* out = (float*)d_out;

    char* ws = (char*)d_ws;
    size_t off = 0;
    auto carve = [&](size_t bytes) { void* p = ws + off; off = (off + bytes + 255) & ~(size_t)255; return p; };
    float* h      = (float*)carve((size_t)NODES * HD * 4);            // 8.4 MB
    __half* h16   = (__half*)carve((size_t)(NODES + 1) * HD * 2);     // 4.2 MB (+dummy row)
    float* xs     = (float*)carve((size_t)NODES * 192 * 4);           // 25.2 MB
    _Float16* wf_hi = (_Float16*)carve(3 * 4 * 6 * 64 * 8 * 2);       // 73.7 KB
    _Float16* wf_lo = (_Float16*)carve(3 * 4 * 6 * 64 * 8 * 2);       // 73.7 KB
    int* cnt_in   = (int*)carve((size_t)NODES * 4);
    int* cnt_out  = (int*)carve((size_t)NODES * 4);
    int* edge_in  = (int*)carve((size_t)NODES * ECAP * 4);            // 12.6 MB
    int* edge_out = (int*)carve((size_t)NODES * ECAP * 4);            // 12.6 MB

    hipMemsetAsync(cnt_out, 0, (size_t)NODES * 4, stream);            // cnt_in needs no memset

    init_h_kernel<<<((NODES + 1) * HD + 255) / 256, 256, 0, stream>>>(attr, Wi, bi, h, h16);
    wprep_kernel<<<(3 * 4 * 6 * 64 * 8 + 255) / 256, 256, 0, stream>>>(Wz, Wr, Wh, wf_hi, wf_lo);
    count_rows_kernel<<<NODES / 4, 256, 0, stream>>>((const float4*)adj, cnt_in, edge_in,
                                                     cnt_out, edge_out);

    for (int step = 0; step < STEPS; ++step) {
        aggregate_kernel<<<NODES / 4, 256, 0, stream>>>(
            (const uint4*)h16, h, cnt_in, edge_in, cnt_out, edge_out, xs);
        gate_kernel<<<NODES / 16, 256, 0, stream>>>(xs, wf_hi, wf_lo, bz, br, bh, h, h16);
    }
    out_kernel<<<NODES * HD / 256, 256, 0, stream>>>(h, Wo, bo, out);
}